// Round 1
// 7964.486 us; speedup vs baseline: 2.2368x; 2.2368x over previous
//
#include <hip/hip_runtime.h>
#include <math.h>

// Problem dims
#define BB   64
#define TT   512
#define LL   256
#define HIDD 256
#define KEYDD 128
#define VALDD 128
#define VOC  4096

__device__ __forceinline__ float sigm(float x){ return 1.0f/(1.0f+__expf(-x)); }

// ---------------------------------------------------------------------------
// Weight transposes (one-time):
// W1T [384][1024]: k<128 -> ctx weight W_ih1[j][256+k]; k>=128 -> W_hh1[j][k-128]
// W2T [384][512]:  k<256 -> W_ih2[j][k];                k>=256 -> W_hh2[j][k-256]
__global__ void prep_w(const float* __restrict__ Wi1, const float* __restrict__ Wh1,
                       const float* __restrict__ Wi2, const float* __restrict__ Wh2,
                       float* __restrict__ W1T, float* __restrict__ W2T){
  int idx = blockIdx.x*blockDim.x + threadIdx.x;
  if (idx < 384*1024){
    int k = idx >> 10, j = idx & 1023;
    W1T[idx] = (k < 128) ? Wi1[j*384 + 256 + k] : Wh1[j*256 + (k-128)];
  }
  if (idx < 384*512){
    int k = idx >> 9, j = idx & 511;
    W2T[idx] = (k < 256) ? Wi2[j*256 + k] : Wh2[j*128 + (k-256)];
  }
}

// key [B][T][K] -> keyT [B][K][T], 32x32 LDS tiles (both sides coalesced)
__global__ __launch_bounds__(256) void prep_keyT(const float* __restrict__ key,
                                                 float* __restrict__ keyT){
  __shared__ float tile[32][33];
  int bid = blockIdx.x;
  int b  = bid >> 6;
  int r  = bid & 63;
  int st = r >> 2, kt = r & 3;         // 16 s-tiles x 4 k-tiles
  int s0 = st*32, k0 = kt*32;
  int tid = threadIdx.x;
  int kl = tid & 31, sl = tid >> 5;
  #pragma unroll
  for (int i = 0; i < 4; ++i)
    tile[sl + 8*i][kl] = key[((size_t)b*TT + s0 + sl + 8*i)*KEYDD + k0 + kl];
  __syncthreads();
  int sl2 = tid & 31, kl2 = tid >> 5;
  #pragma unroll
  for (int i = 0; i < 4; ++i)
    keyT[((size_t)b*KEYDD + k0 + kl2 + 8*i)*TT + s0 + sl2] = tile[sl2][kl2 + 8*i];
}

// ---------------------------------------------------------------------------
// P1[n][j] = sum_{k<256} emb[text[n]][k] * W_ih1[j][k] + bi1[j] + bh1[j]
// 128x128 tile SGEMM with gathered A rows. M=16384, N=1024, K=256.
__global__ __launch_bounds__(256) void pre_gemm(
    const int*   __restrict__ text, const float* __restrict__ emb,
    const float* __restrict__ Wi1,  const float* __restrict__ bi1,
    const float* __restrict__ bh1,  float* __restrict__ P1)
{
  __shared__ float As[16][132];
  __shared__ float Bs[16][132];
  const int tid = threadIdx.x;
  const int tx = tid & 15, ty = tid >> 4;
  const int bn = blockIdx.x, bm = blockIdx.y;

  float acc[8][8];
  #pragma unroll
  for (int i = 0; i < 8; ++i)
    #pragma unroll
    for (int j = 0; j < 8; ++j) acc[i][j] = 0.f;

  const int r  = tid >> 1;
  const int ko = (tid & 1) * 8;
  const int arow = text[bm*128 + r];
  const float* Ap = emb + (size_t)arow*256 + ko;
  const float* Bp = Wi1 + (size_t)(bn*128 + r)*384 + ko;

  for (int k0 = 0; k0 < 256; k0 += 16){
    float4 a0 = *(const float4*)(Ap + k0);
    float4 a1 = *(const float4*)(Ap + k0 + 4);
    float4 b0 = *(const float4*)(Bp + k0);
    float4 b1 = *(const float4*)(Bp + k0 + 4);
    As[ko+0][r]=a0.x; As[ko+1][r]=a0.y; As[ko+2][r]=a0.z; As[ko+3][r]=a0.w;
    As[ko+4][r]=a1.x; As[ko+5][r]=a1.y; As[ko+6][r]=a1.z; As[ko+7][r]=a1.w;
    Bs[ko+0][r]=b0.x; Bs[ko+1][r]=b0.y; Bs[ko+2][r]=b0.z; Bs[ko+3][r]=b0.w;
    Bs[ko+4][r]=b1.x; Bs[ko+5][r]=b1.y; Bs[ko+6][r]=b1.z; Bs[ko+7][r]=b1.w;
    __syncthreads();
    #pragma unroll
    for (int k = 0; k < 16; ++k){
      float4 x0 = *(const float4*)&As[k][ty*8];
      float4 x1 = *(const float4*)&As[k][ty*8+4];
      float4 y0 = *(const float4*)&Bs[k][tx*8];
      float4 y1 = *(const float4*)&Bs[k][tx*8+4];
      float av[8] = {x0.x,x0.y,x0.z,x0.w,x1.x,x1.y,x1.z,x1.w};
      float bv[8] = {y0.x,y0.y,y0.z,y0.w,y1.x,y1.y,y1.z,y1.w};
      #pragma unroll
      for (int i = 0; i < 8; ++i)
        #pragma unroll
        for (int j = 0; j < 8; ++j) acc[i][j] += av[i]*bv[j];
    }
    __syncthreads();
  }

  const int c0 = bn*128 + tx*8;
  float bl[8];
  #pragma unroll
  for (int j = 0; j < 8; ++j) bl[j] = bi1[c0 + j] + bh1[c0 + j];
  #pragma unroll
  for (int i = 0; i < 8; ++i){
    size_t row = (size_t)(bm*128 + ty*8 + i);
    float4 o0 = make_float4(acc[i][0]+bl[0], acc[i][1]+bl[1], acc[i][2]+bl[2], acc[i][3]+bl[3]);
    float4 o1 = make_float4(acc[i][4]+bl[4], acc[i][5]+bl[5], acc[i][6]+bl[6], acc[i][7]+bl[7]);
    *(float4*)(P1 + row*1024 + c0)     = o0;
    *(float4*)(P1 + row*1024 + c0 + 4) = o1;
  }
}

// ---------------------------------------------------------------------------
// Recurrence. One block per batch element, 1024 threads.
// All weight streams are float4 (16B/lane) with split-K + LDS partial reduce.
__global__ __launch_bounds__(1024) void rec_kernel(
    const float* __restrict__ keyT, const float* __restrict__ values,
    const float* __restrict__ P1,   const float* __restrict__ W1T,
    const float* __restrict__ W2T,  const float* __restrict__ bi2,
    const float* __restrict__ bh2,  float* __restrict__ states)
{
  const int b   = blockIdx.x;
  const int tid = threadIdx.x;

  __shared__ __align__(16) float ST[512];     // [ctx 0:128 | h1 128:384 | h2 384:512]
  __shared__ __align__(16) float part[4096];  // split-K partials (16 KB, reused per stage)
  __shared__ float att[512];
  __shared__ float b2s[512];
  __shared__ float red[16];

  float c1 = 0.f, c2 = 0.f;                   // cell states live in registers (tid<256 / tid<128)
  if (tid < 512){ ST[tid] = 0.f; b2s[tid] = bi2[tid] + bh2[tid]; }
  __syncthreads();

  const float*  P1row = P1 + (size_t)b*LL*1024;
  const float4* keyT4 = reinterpret_cast<const float4*>(keyT + (size_t)b*KEYDD*TT);
  const float4* val4  = reinterpret_cast<const float4*>(values + (size_t)b*TT*VALDD);

  // thread role decompositions
  const int j4a = tid & 255, kca = tid >> 8;  // LSTM1: 256 out-groups x 4 K-chunks(96)
  const int j4b = tid & 127, kcb = tid >> 7;  // LSTM2/energy: 128 groups x 8 chunks
  const int v4c = tid & 31,  chc = tid >> 5;  // ctx: 32 v-groups x 32 s-chunks(16)

  for (int t = 0; t < LL; ++t, P1row += 1024){
    // prefetch this step's precomputed gate biases (overlaps the partial loop)
    float p1v0=0.f, p1v1=0.f, p1v2=0.f, p1v3=0.f;
    if (tid < 256){
      p1v0 = P1row[tid];       p1v1 = P1row[256+tid];
      p1v2 = P1row[512+tid];   p1v3 = P1row[768+tid];
    }

    // ---- LSTM1 partials: g1[4j4a..+3] over k in [kca*96, kca*96+96), inputs ST[0:384)
    {
      const float4* wp = reinterpret_cast<const float4*>(W1T) + (size_t)(kca*96)*256 + j4a;
      float4 acc = make_float4(0.f,0.f,0.f,0.f);
      #pragma unroll 4
      for (int i = 0; i < 24; ++i){
        float4 x  = *reinterpret_cast<const float4*>(&ST[kca*96 + 4*i]);
        float4 w0 = wp[0], w1 = wp[256], w2 = wp[512], w3 = wp[768];
        wp += 1024;
        acc.x += x.x*w0.x + x.y*w1.x + x.z*w2.x + x.w*w3.x;
        acc.y += x.x*w0.y + x.y*w1.y + x.z*w2.y + x.w*w3.y;
        acc.z += x.x*w0.z + x.y*w1.z + x.z*w2.z + x.w*w3.z;
        acc.w += x.x*w0.w + x.y*w1.w + x.z*w2.w + x.w*w3.w;
      }
      *reinterpret_cast<float4*>(&part[kca*1024 + 4*j4a]) = acc;
    }
    __syncthreads();

    // ---- LSTM1 gates (i,f,g,o at j = tid, tid+256, tid+512, tid+768)
    if (tid < 256){
      float s0 = p1v0, s1 = p1v1, s2 = p1v2, s3 = p1v3;
      #pragma unroll
      for (int kc = 0; kc < 4; ++kc){
        const float* pp = &part[kc*1024];
        s0 += pp[tid]; s1 += pp[256+tid]; s2 += pp[512+tid]; s3 += pp[768+tid];
      }
      float c = sigm(s1)*c1 + sigm(s0)*tanhf(s2);
      c1 = c;
      ST[128+tid] = sigm(s3)*tanhf(c);           // h1 new
    }
    __syncthreads();

    // ---- LSTM2 partials: inputs ST[128:512) (h1new | h2old), k in [kcb*48, +48)
    {
      const float4* wp = reinterpret_cast<const float4*>(W2T) + (size_t)(kcb*48)*128 + j4b;
      float4 acc = make_float4(0.f,0.f,0.f,0.f);
      #pragma unroll 4
      for (int i = 0; i < 12; ++i){
        float4 x  = *reinterpret_cast<const float4*>(&ST[128 + kcb*48 + 4*i]);
        float4 w0 = wp[0], w1 = wp[128], w2 = wp[256], w3 = wp[384];
        wp += 512;
        acc.x += x.x*w0.x + x.y*w1.x + x.z*w2.x + x.w*w3.x;
        acc.y += x.x*w0.y + x.y*w1.y + x.z*w2.y + x.w*w3.y;
        acc.z += x.x*w0.z + x.y*w1.z + x.z*w2.z + x.w*w3.z;
        acc.w += x.x*w0.w + x.y*w1.w + x.z*w2.w + x.w*w3.w;
      }
      *reinterpret_cast<float4*>(&part[kcb*512 + 4*j4b]) = acc;
    }
    __syncthreads();

    // ---- LSTM2 gates + h2 store
    if (tid < 128){
      float s0 = b2s[tid], s1 = b2s[128+tid], s2 = b2s[256+tid], s3 = b2s[384+tid];
      #pragma unroll
      for (int kc = 0; kc < 8; ++kc){
        const float* pp = &part[kc*512];
        s0 += pp[tid]; s1 += pp[128+tid]; s2 += pp[256+tid]; s3 += pp[384+tid];
      }
      float c = sigm(s1)*c2 + sigm(s0)*tanhf(s2);
      c2 = c;
      float h2 = sigm(s3)*tanhf(c);
      ST[384+tid] = h2;
      states[((size_t)b*LL + t)*256 + tid] = h2;
    }
    __syncthreads();

    // ---- attention energies: e[s] = sum_k keyT[k][s]*h2[k]   (coalesced float4 along s)
    {
      const float4* kp = keyT4 + (size_t)(kcb*16)*128 + j4b;   // row k = 128 float4
      float4 acc = make_float4(0.f,0.f,0.f,0.f);
      #pragma unroll 4
      for (int kk = 0; kk < 16; ++kk){
        float  h  = ST[384 + kcb*16 + kk];
        float4 kv = kp[kk*128];
        acc.x += h*kv.x; acc.y += h*kv.y; acc.z += h*kv.z; acc.w += h*kv.w;
      }
      *reinterpret_cast<float4*>(&part[kcb*512 + 4*j4b]) = acc;
    }
    __syncthreads();

    // ---- energy reduce + softmax over 512
    {
      float e = -3.4e38f;
      if (tid < 512){
        e = part[tid]      + part[512+tid]  + part[1024+tid] + part[1536+tid]
          + part[2048+tid] + part[2560+tid] + part[3072+tid] + part[3584+tid];
      }
      float m = e;
      #pragma unroll
      for (int off = 32; off > 0; off >>= 1) m = fmaxf(m, __shfl_xor(m, off));
      if (tid < 512 && (tid & 63) == 0) red[tid >> 6] = m;
      __syncthreads();
      float M = fmaxf(fmaxf(fmaxf(red[0],red[1]),fmaxf(red[2],red[3])),
                      fmaxf(fmaxf(red[4],red[5]),fmaxf(red[6],red[7])));
      float ex = (tid < 512) ? __expf(e - M) : 0.f;
      float ssum = ex;
      #pragma unroll
      for (int off = 32; off > 0; off >>= 1) ssum += __shfl_xor(ssum, off);
      if (tid < 512 && (tid & 63) == 0) red[8 + (tid >> 6)] = ssum;
      __syncthreads();
      float S = ((red[8]+red[9])+(red[10]+red[11]))+((red[12]+red[13])+(red[14]+red[15]));
      float inv = 1.0f / S;
      if (tid < 512) att[tid] = ex * inv;
    }
    __syncthreads();

    // ---- context partials: ctx[4v4c..+3] over s in [chc*16, +16)
    {
      const float4* vp = val4 + (size_t)(chc*16)*32 + v4c;     // values row s = 32 float4
      float4 acc = make_float4(0.f,0.f,0.f,0.f);
      #pragma unroll 4
      for (int s = 0; s < 16; ++s){
        float  a  = att[chc*16 + s];
        float4 vv = vp[s*32];
        acc.x += a*vv.x; acc.y += a*vv.y; acc.z += a*vv.z; acc.w += a*vv.w;
      }
      *reinterpret_cast<float4*>(&part[chc*128 + 4*v4c]) = acc;
    }
    __syncthreads();

    // ---- context reduce + store (ctx feeds next step's LSTM1)
    if (tid < 128){
      float cx = 0.f;
      #pragma unroll
      for (int ch = 0; ch < 32; ++ch) cx += part[ch*128 + tid];
      ST[tid] = cx;
      states[((size_t)b*LL + t)*256 + 128 + tid] = cx;
    }
    __syncthreads();
  }
}

// ---------------------------------------------------------------------------
// Final logits GEMM: C[n][v] = states[n][:] . emb[v][:] + b_out[v]   (unchanged)
__global__ __launch_bounds__(256) void gemm_kernel(
    const float* __restrict__ A, const float* __restrict__ Bm,
    const float* __restrict__ bias, float* __restrict__ C)
{
  __shared__ float As[16][132];
  __shared__ float Bs[16][132];
  const int tid = threadIdx.x;
  const int tx = tid & 15, ty = tid >> 4;
  const int bn = blockIdx.x, bm = blockIdx.y;

  float acc[8][8];
  #pragma unroll
  for (int i = 0; i < 8; ++i)
    #pragma unroll
    for (int j = 0; j < 8; ++j) acc[i][j] = 0.f;

  const int r  = tid >> 1;
  const int ko = (tid & 1) * 8;
  const float* Ap = A  + ((size_t)(bm*128 + r))*256 + ko;
  const float* Bp = Bm + ((size_t)(bn*128 + r))*256 + ko;

  for (int k0 = 0; k0 < 256; k0 += 16){
    float4 a0 = *(const float4*)(Ap + k0);
    float4 a1 = *(const float4*)(Ap + k0 + 4);
    float4 b0 = *(const float4*)(Bp + k0);
    float4 b1 = *(const float4*)(Bp + k0 + 4);
    As[ko+0][r]=a0.x; As[ko+1][r]=a0.y; As[ko+2][r]=a0.z; As[ko+3][r]=a0.w;
    As[ko+4][r]=a1.x; As[ko+5][r]=a1.y; As[ko+6][r]=a1.z; As[ko+7][r]=a1.w;
    Bs[ko+0][r]=b0.x; Bs[ko+1][r]=b0.y; Bs[ko+2][r]=b0.z; Bs[ko+3][r]=b0.w;
    Bs[ko+4][r]=b1.x; Bs[ko+5][r]=b1.y; Bs[ko+6][r]=b1.z; Bs[ko+7][r]=b1.w;
    __syncthreads();
    #pragma unroll
    for (int k = 0; k < 16; ++k){
      float4 x0 = *(const float4*)&As[k][ty*8];
      float4 x1 = *(const float4*)&As[k][ty*8+4];
      float4 y0 = *(const float4*)&Bs[k][tx*8];
      float4 y1 = *(const float4*)&Bs[k][tx*8+4];
      float av[8] = {x0.x,x0.y,x0.z,x0.w,x1.x,x1.y,x1.z,x1.w};
      float bv[8] = {y0.x,y0.y,y0.z,y0.w,y1.x,y1.y,y1.z,y1.w};
      #pragma unroll
      for (int i = 0; i < 8; ++i)
        #pragma unroll
        for (int j = 0; j < 8; ++j) acc[i][j] += av[i]*bv[j];
    }
    __syncthreads();
  }

  const int c0 = bn*128 + tx*8;
  float bl[8];
  #pragma unroll
  for (int j = 0; j < 8; ++j) bl[j] = bias[c0 + j];
  #pragma unroll
  for (int i = 0; i < 8; ++i){
    size_t row = (size_t)(bm*128 + ty*8 + i);
    float4 o0 = make_float4(acc[i][0]+bl[0], acc[i][1]+bl[1], acc[i][2]+bl[2], acc[i][3]+bl[3]);
    float4 o1 = make_float4(acc[i][4]+bl[4], acc[i][5]+bl[5], acc[i][6]+bl[6], acc[i][7]+bl[7]);
    *(float4*)(C + row*4096 + c0)     = o0;
    *(float4*)(C + row*4096 + c0 + 4) = o1;
  }
}

extern "C" void kernel_launch(void* const* d_in, const int* in_sizes, int n_in,
                              void* d_out, int out_size, void* d_ws, size_t ws_size,
                              hipStream_t stream)
{
  const float* key    = (const float*)d_in[0];
  const float* values = (const float*)d_in[1];
  // d_in[2] = lens (unused by reference path)
  const int*   text   = (const int*)  d_in[3];
  const float* emb    = (const float*)d_in[4];
  const float* Wi1    = (const float*)d_in[5];
  const float* Wh1    = (const float*)d_in[6];
  const float* bi1    = (const float*)d_in[7];
  const float* bh1    = (const float*)d_in[8];
  const float* Wi2    = (const float*)d_in[9];
  const float* Wh2    = (const float*)d_in[10];
  const float* bi2    = (const float*)d_in[11];
  const float* bh2    = (const float*)d_in[12];
  const float* bout   = (const float*)d_in[13];

  // workspace (floats): states[16384*256] | W1T[384*1024] | W2T[384*512]  (~18.3 MB)
  float* states = (float*)d_ws;
  float* W1T    = states + (size_t)BB*LL*256;
  float* W2T    = W1T + 384*1024;

  // scratch inside d_out (268 MB total; dead until final GEMM overwrites it):
  // P1[16384*1024] (64 MB) | keyT[64*128*512] (16 MB)
  float* P1   = (float*)d_out;
  float* keyT = P1 + (size_t)16384*1024;

  prep_w   <<<1536, 256, 0, stream>>>(Wi1, Wh1, Wi2, Wh2, W1T, W2T);
  prep_keyT<<<4096, 256, 0, stream>>>(key, keyT);
  pre_gemm <<<dim3(1024/128, 16384/128), 256, 0, stream>>>(text, emb, Wi1, bi1, bh1, P1);
  rec_kernel<<<BB, 1024, 0, stream>>>(keyT, values, P1, W1T, W2T, bi2, bh2, states);
  dim3 grid(VOC/128, (BB*LL)/128);
  gemm_kernel<<<grid, 256, 0, stream>>>(states, emb, bout, (float*)d_out);
}

// Round 2
// 7553.940 us; speedup vs baseline: 2.3584x; 1.0543x over previous
//
#include <hip/hip_runtime.h>
#include <math.h>

// Problem dims
#define BB   64
#define TT   512
#define LL   256
#define HIDD 256
#define KEYDD 128
#define VALDD 128
#define VOC  4096
#define NB   4        // blocks cooperating per batch element

__device__ __forceinline__ float sigm(float x){ return 1.0f/(1.0f+__expf(-x)); }

// Cluster barrier among NB blocks: monotonic counter, agent-scope release/acquire.
// __syncthreads drains all threads' stores to L2; tid0's release atomic writes back
// the XCD L2; acquire spin invalidates stale L1/L2 before readers proceed.
__device__ __forceinline__ void cluster_sync(unsigned int* c, unsigned int target){
  __syncthreads();
  if (threadIdx.x == 0){
    __hip_atomic_fetch_add(c, 1u, __ATOMIC_RELEASE, __HIP_MEMORY_SCOPE_AGENT);
    while (__hip_atomic_load(c, __ATOMIC_ACQUIRE, __HIP_MEMORY_SCOPE_AGENT) < target)
      __builtin_amdgcn_s_sleep(2);
  }
  __syncthreads();
}

// ---------------------------------------------------------------------------
// One-time weight reshapes into per-slice-contiguous layouts + counter zeroing.
// W1T [NB][384][256]: slice r, row k, col jj (jj = gate*64 + cell-within-slice)
//   k<128 -> ctx weight Wi1[j][256+k]; k>=128 -> Wh1[j][k-128]; j = (jj>>6)*256 + r*64 + (jj&63)
// W2T [NB][384][128]: k<256 -> Wi2[j][k]; k>=256 -> Wh2[j][k-256]; j = (jj>>5)*128 + r*32 + (jj&31)
__global__ void prep_w(const float* __restrict__ Wi1, const float* __restrict__ Wh1,
                       const float* __restrict__ Wi2, const float* __restrict__ Wh2,
                       float* __restrict__ W1T, float* __restrict__ W2T,
                       unsigned int* __restrict__ cnt){
  int idx = blockIdx.x*blockDim.x + threadIdx.x;
  if (idx < NB*384*256){
    int r  = idx / (384*256);
    int rm = idx - r*(384*256);
    int k  = rm >> 8, jj = rm & 255;
    int j  = (jj >> 6)*256 + r*64 + (jj & 63);
    W1T[idx] = (k < 128) ? Wi1[j*384 + 256 + k] : Wh1[j*256 + (k-128)];
  }
  if (idx < NB*384*128){
    int r  = idx / (384*128);
    int rm = idx - r*(384*128);
    int k  = rm >> 7, jj = rm & 127;
    int j  = (jj >> 5)*128 + r*32 + (jj & 31);
    W2T[idx] = (k < 256) ? Wi2[j*256 + k] : Wh2[j*128 + (k-256)];
  }
  if (idx < BB*NB) cnt[idx] = 0;
}

// key [B][T][K] -> keyT [B][K][T], 32x32 LDS tiles (both sides coalesced)
__global__ __launch_bounds__(256) void prep_keyT(const float* __restrict__ key,
                                                 float* __restrict__ keyT){
  __shared__ float tile[32][33];
  int bid = blockIdx.x;
  int b  = bid >> 6;
  int r  = bid & 63;
  int st = r >> 2, kt = r & 3;
  int s0 = st*32, k0 = kt*32;
  int tid = threadIdx.x;
  int kl = tid & 31, sl = tid >> 5;
  #pragma unroll
  for (int i = 0; i < 4; ++i)
    tile[sl + 8*i][kl] = key[((size_t)b*TT + s0 + sl + 8*i)*KEYDD + k0 + kl];
  __syncthreads();
  int sl2 = tid & 31, kl2 = tid >> 5;
  #pragma unroll
  for (int i = 0; i < 4; ++i)
    keyT[((size_t)b*KEYDD + k0 + kl2 + 8*i)*TT + s0 + sl2] = tile[sl2][kl2 + 8*i];
}

// ---------------------------------------------------------------------------
// P1[n][j] = sum_{k<256} emb[text[n]][k] * W_ih1[j][k] + bi1[j] + bh1[j]
__global__ __launch_bounds__(256) void pre_gemm(
    const int*   __restrict__ text, const float* __restrict__ emb,
    const float* __restrict__ Wi1,  const float* __restrict__ bi1,
    const float* __restrict__ bh1,  float* __restrict__ P1)
{
  __shared__ float As[16][132];
  __shared__ float Bs[16][132];
  const int tid = threadIdx.x;
  const int tx = tid & 15, ty = tid >> 4;
  const int bn = blockIdx.x, bm = blockIdx.y;

  float acc[8][8];
  #pragma unroll
  for (int i = 0; i < 8; ++i)
    #pragma unroll
    for (int j = 0; j < 8; ++j) acc[i][j] = 0.f;

  const int r  = tid >> 1;
  const int ko = (tid & 1) * 8;
  const int arow = text[bm*128 + r];
  const float* Ap = emb + (size_t)arow*256 + ko;
  const float* Bp = Wi1 + (size_t)(bn*128 + r)*384 + ko;

  for (int k0 = 0; k0 < 256; k0 += 16){
    float4 a0 = *(const float4*)(Ap + k0);
    float4 a1 = *(const float4*)(Ap + k0 + 4);
    float4 b0 = *(const float4*)(Bp + k0);
    float4 b1 = *(const float4*)(Bp + k0 + 4);
    As[ko+0][r]=a0.x; As[ko+1][r]=a0.y; As[ko+2][r]=a0.z; As[ko+3][r]=a0.w;
    As[ko+4][r]=a1.x; As[ko+5][r]=a1.y; As[ko+6][r]=a1.z; As[ko+7][r]=a1.w;
    Bs[ko+0][r]=b0.x; Bs[ko+1][r]=b0.y; Bs[ko+2][r]=b0.z; Bs[ko+3][r]=b0.w;
    Bs[ko+4][r]=b1.x; Bs[ko+5][r]=b1.y; Bs[ko+6][r]=b1.z; Bs[ko+7][r]=b1.w;
    __syncthreads();
    #pragma unroll
    for (int k = 0; k < 16; ++k){
      float4 x0 = *(const float4*)&As[k][ty*8];
      float4 x1 = *(const float4*)&As[k][ty*8+4];
      float4 y0 = *(const float4*)&Bs[k][tx*8];
      float4 y1 = *(const float4*)&Bs[k][tx*8+4];
      float av[8] = {x0.x,x0.y,x0.z,x0.w,x1.x,x1.y,x1.z,x1.w};
      float bv[8] = {y0.x,y0.y,y0.z,y0.w,y1.x,y1.y,y1.z,y1.w};
      #pragma unroll
      for (int i = 0; i < 8; ++i)
        #pragma unroll
        for (int j = 0; j < 8; ++j) acc[i][j] += av[i]*bv[j];
    }
    __syncthreads();
  }

  const int c0 = bn*128 + tx*8;
  float bl[8];
  #pragma unroll
  for (int j = 0; j < 8; ++j) bl[j] = bi1[c0 + j] + bh1[c0 + j];
  #pragma unroll
  for (int i = 0; i < 8; ++i){
    size_t row = (size_t)(bm*128 + ty*8 + i);
    float4 o0 = make_float4(acc[i][0]+bl[0], acc[i][1]+bl[1], acc[i][2]+bl[2], acc[i][3]+bl[3]);
    float4 o1 = make_float4(acc[i][4]+bl[4], acc[i][5]+bl[5], acc[i][6]+bl[6], acc[i][7]+bl[7]);
    *(float4*)(P1 + row*1024 + c0)     = o0;
    *(float4*)(P1 + row*1024 + c0 + 4) = o1;
  }
}

// ---------------------------------------------------------------------------
// Recurrence: NB=4 blocks per batch element, 1024 threads each (grid = 256 = #CUs).
// Block r owns: h1 cells [64r,64r+64), h2 cells [32r,32r+32), attention s in [128r,128r+128).
// Slices exchanged via global buffers with 3 cluster syncs per timestep.
__global__ __launch_bounds__(1024) void rec_kernel(
    const float* __restrict__ keyT, const float* __restrict__ values,
    const float* __restrict__ P1,   const float* __restrict__ W1T,
    const float* __restrict__ W2T,  const float* __restrict__ bi2,
    const float* __restrict__ bh2,  float* __restrict__ states,
    float* __restrict__ h1buf, float* __restrict__ h2buf,
    float* __restrict__ axc,  unsigned int* __restrict__ cnt)
{
  const int bid = blockIdx.x;
  const int b = bid >> 2, r = bid & 3;
  const int tid = threadIdx.x;

  __shared__ __align__(16) float ST[512];     // [ctx 0:128 | h1 128:384 | h2 384:512] (full vectors)
  __shared__ __align__(16) float part[4096];  // split-K partials (16 KB, reused per phase)
  __shared__ float g1s[256];                  // gate sums / energy scratch
  __shared__ float att[128];                  // local softmax numerators
  __shared__ float b2loc[128];
  __shared__ float red[8];

  if (tid < 512) ST[tid] = 0.f;
  if (tid < 128){
    int j = (tid >> 5)*128 + r*32 + (tid & 31);
    b2loc[tid] = bi2[j] + bh2[j];
  }
  float c1 = 0.f, c2 = 0.f;   // cell-state slices live in registers (tid<64 / tid<32)
  __syncthreads();

  const float4* W1r  = reinterpret_cast<const float4*>(W1T + (size_t)r*384*256);
  const float4* W2r  = reinterpret_cast<const float4*>(W2T + (size_t)r*384*128);
  const float4* keyB = reinterpret_cast<const float4*>(keyT + (size_t)b*KEYDD*TT);
  const float4* valB = reinterpret_cast<const float4*>(values + (size_t)b*TT*VALDD);
  const float*  P1row = P1 + (size_t)b*LL*1024;
  unsigned int* cp = cnt + b*NB;              // per-batch counters, phases 0..2
  float* axb = axc + (size_t)b*NB*132;

  const int ogA = tid & 63, kcA = tid >> 6;   // A: 64 out-groups(x4) x 16 k-chunks(24)
  const int ogB = tid & 31, kcB = tid >> 5;   // B: 32 out-groups(x4) x 32 k-chunks(12)

  for (int t = 0; t < LL; ++t, P1row += 1024){
    // prefetch precomputed embedding-GEMM term for this block's gate outputs
    float p1v = (tid < 256) ? P1row[(tid >> 6)*256 + r*64 + (tid & 63)] : 0.f;

    // ---- phase A: LSTM1 gate partials over k-chunks (inputs ST[0:384) = [ctx|h1])
    {
      const float4* wp = W1r + (size_t)(kcA*24)*64 + ogA;
      float4 acc = make_float4(0.f,0.f,0.f,0.f);
      #pragma unroll 8
      for (int i = 0; i < 24; ++i){
        float4 w = wp[(size_t)i*64];
        float  x = ST[kcA*24 + i];
        acc.x += x*w.x; acc.y += x*w.y; acc.z += x*w.z; acc.w += x*w.w;
      }
      *reinterpret_cast<float4*>(&part[kcA*256 + ogA*4]) = acc;
    }
    __syncthreads();
    if (tid < 256){
      float s = p1v;
      #pragma unroll
      for (int kc = 0; kc < 16; ++kc) s += part[kc*256 + tid];
      g1s[tid] = s;
    }
    __syncthreads();
    if (tid < 64){
      float gi = sigm(g1s[tid]),     gf = sigm(g1s[64+tid]);
      float gg = tanhf(g1s[128+tid]), go = sigm(g1s[192+tid]);
      float c = gf*c1 + gi*gg; c1 = c;
      h1buf[b*256 + r*64 + tid] = go*tanhf(c);
    }
    cluster_sync(cp+0, (unsigned)((t+1)*NB));
    if (tid < 256) ST[128+tid] = h1buf[b*256 + tid];
    __syncthreads();

    // ---- phase B: LSTM2 gate partials (inputs ST[128:512) = [h1|h2])
    {
      const float4* wp = W2r + (size_t)(kcB*12)*32 + ogB;
      float4 acc = make_float4(0.f,0.f,0.f,0.f);
      #pragma unroll 6
      for (int i = 0; i < 12; ++i){
        float4 w = wp[(size_t)i*32];
        float  x = ST[128 + kcB*12 + i];
        acc.x += x*w.x; acc.y += x*w.y; acc.z += x*w.z; acc.w += x*w.w;
      }
      *reinterpret_cast<float4*>(&part[kcB*128 + ogB*4]) = acc;
    }
    __syncthreads();
    if (tid < 128){
      float s = b2loc[tid];
      #pragma unroll
      for (int kc = 0; kc < 32; ++kc) s += part[kc*128 + tid];
      g1s[tid] = s;
    }
    __syncthreads();
    if (tid < 32){
      float gi = sigm(g1s[tid]),     gf = sigm(g1s[32+tid]);
      float gg = tanhf(g1s[64+tid]), go = sigm(g1s[96+tid]);
      float c = gf*c2 + gi*gg; c2 = c;
      float h2 = go*tanhf(c);
      h2buf[b*128 + r*32 + tid] = h2;
      states[((size_t)b*LL + t)*256 + r*32 + tid] = h2;   // h2 slice of output row
    }
    cluster_sync(cp+1, (unsigned)((t+1)*NB));
    if (tid < 128) ST[384+tid] = h2buf[b*128 + tid];
    __syncthreads();

    // ---- phase C: attention on s-slice [128r, 128r+128)
    {
      const int sg = tid & 31, kc = tid >> 5;   // 32 s-groups(x4) x 32 k-chunks(4)
      const float4* kp = keyB + (size_t)(kc*4)*128 + r*32 + sg;
      float4 acc = make_float4(0.f,0.f,0.f,0.f);
      #pragma unroll
      for (int i = 0; i < 4; ++i){
        float4 kv = kp[(size_t)i*128];
        float  h  = ST[384 + kc*4 + i];
        acc.x += h*kv.x; acc.y += h*kv.y; acc.z += h*kv.z; acc.w += h*kv.w;
      }
      *reinterpret_cast<float4*>(&part[kc*128 + sg*4]) = acc;
    }
    __syncthreads();
    float m_r, s_r;
    {
      float e = -3.4e38f;
      if (tid < 128){
        e = 0.f;
        #pragma unroll
        for (int kc = 0; kc < 32; ++kc) e += part[kc*128 + tid];
      }
      float m = e;
      #pragma unroll
      for (int off = 32; off > 0; off >>= 1) m = fmaxf(m, __shfl_xor(m, off));
      if (tid == 0)  red[0] = m;
      if (tid == 64) red[1] = m;
      __syncthreads();
      m_r = fmaxf(red[0], red[1]);
      float p = (tid < 128) ? __expf(e - m_r) : 0.f;
      if (tid < 128) att[tid] = p;
      float ss = p;
      #pragma unroll
      for (int off = 32; off > 0; off >>= 1) ss += __shfl_xor(ss, off);
      if (tid == 0)  red[2] = ss;
      if (tid == 64) red[3] = ss;
      __syncthreads();
      s_r = red[2] + red[3];
    }
    {
      const int vg = tid & 31, sc = tid >> 5;   // 32 v-groups(x4) x 32 s-chunks(4)
      const float4* vp = valB + (size_t)(r*128 + sc*4)*32 + vg;
      float4 acc = make_float4(0.f,0.f,0.f,0.f);
      #pragma unroll
      for (int i = 0; i < 4; ++i){
        float4 vv = vp[(size_t)i*32];
        float  a  = att[sc*4 + i];
        acc.x += a*vv.x; acc.y += a*vv.y; acc.z += a*vv.z; acc.w += a*vv.w;
      }
      *reinterpret_cast<float4*>(&part[sc*128 + vg*4]) = acc;
    }
    __syncthreads();
    if (tid < 128){
      float cx = 0.f;
      #pragma unroll
      for (int kc = 0; kc < 32; ++kc) cx += part[kc*128 + tid];
      axb[r*132 + tid] = cx;
    }
    if (tid == 0){ axb[r*132 + 128] = m_r; axb[r*132 + 129] = s_r; }
    cluster_sync(cp+2, (unsigned)((t+1)*NB));

    // ---- flash-style combine of 4 softmax slices -> full ctx
    if (tid < 128){
      float m0 = axb[128],      m1 = axb[132+128];
      float m2 = axb[264+128],  m3 = axb[396+128];
      float M  = fmaxf(fmaxf(m0,m1), fmaxf(m2,m3));
      float w0 = __expf(m0-M), w1 = __expf(m1-M), w2 = __expf(m2-M), w3 = __expf(m3-M);
      float inv = 1.0f / (w0*axb[129] + w1*axb[132+129] + w2*axb[264+129] + w3*axb[396+129]);
      float cx = (w0*axb[tid] + w1*axb[132+tid] + w2*axb[264+tid] + w3*axb[396+tid]) * inv;
      ST[tid] = cx;                                        // ctx feeds next step's LSTM1
      if ((tid >> 5) == r)
        states[((size_t)b*LL + t)*256 + 128 + tid] = cx;   // ctx slice of output row
    }
    __syncthreads();
  }
}

// ---------------------------------------------------------------------------
// Final logits GEMM: C[n][v] = states[n][:] . emb[v][:] + b_out[v]
__global__ __launch_bounds__(256) void gemm_kernel(
    const float* __restrict__ A, const float* __restrict__ Bm,
    const float* __restrict__ bias, float* __restrict__ C)
{
  __shared__ float As[16][132];
  __shared__ float Bs[16][132];
  const int tid = threadIdx.x;
  const int tx = tid & 15, ty = tid >> 4;
  const int bn = blockIdx.x, bm = blockIdx.y;

  float acc[8][8];
  #pragma unroll
  for (int i = 0; i < 8; ++i)
    #pragma unroll
    for (int j = 0; j < 8; ++j) acc[i][j] = 0.f;

  const int r  = tid >> 1;
  const int ko = (tid & 1) * 8;
  const float* Ap = A  + ((size_t)(bm*128 + r))*256 + ko;
  const float* Bp = Bm + ((size_t)(bn*128 + r))*256 + ko;

  for (int k0 = 0; k0 < 256; k0 += 16){
    float4 a0 = *(const float4*)(Ap + k0);
    float4 a1 = *(const float4*)(Ap + k0 + 4);
    float4 b0 = *(const float4*)(Bp + k0);
    float4 b1 = *(const float4*)(Bp + k0 + 4);
    As[ko+0][r]=a0.x; As[ko+1][r]=a0.y; As[ko+2][r]=a0.z; As[ko+3][r]=a0.w;
    As[ko+4][r]=a1.x; As[ko+5][r]=a1.y; As[ko+6][r]=a1.z; As[ko+7][r]=a1.w;
    Bs[ko+0][r]=b0.x; Bs[ko+1][r]=b0.y; Bs[ko+2][r]=b0.z; Bs[ko+3][r]=b0.w;
    Bs[ko+4][r]=b1.x; Bs[ko+5][r]=b1.y; Bs[ko+6][r]=b1.z; Bs[ko+7][r]=b1.w;
    __syncthreads();
    #pragma unroll
    for (int k = 0; k < 16; ++k){
      float4 x0 = *(const float4*)&As[k][ty*8];
      float4 x1 = *(const float4*)&As[k][ty*8+4];
      float4 y0 = *(const float4*)&Bs[k][tx*8];
      float4 y1 = *(const float4*)&Bs[k][tx*8+4];
      float av[8] = {x0.x,x0.y,x0.z,x0.w,x1.x,x1.y,x1.z,x1.w};
      float bv[8] = {y0.x,y0.y,y0.z,y0.w,y1.x,y1.y,y1.z,y1.w};
      #pragma unroll
      for (int i = 0; i < 8; ++i)
        #pragma unroll
        for (int j = 0; j < 8; ++j) acc[i][j] += av[i]*bv[j];
    }
    __syncthreads();
  }

  const int c0 = bn*128 + tx*8;
  float bl[8];
  #pragma unroll
  for (int j = 0; j < 8; ++j) bl[j] = bias[c0 + j];
  #pragma unroll
  for (int i = 0; i < 8; ++i){
    size_t row = (size_t)(bm*128 + ty*8 + i);
    float4 o0 = make_float4(acc[i][0]+bl[0], acc[i][1]+bl[1], acc[i][2]+bl[2], acc[i][3]+bl[3]);
    float4 o1 = make_float4(acc[i][4]+bl[4], acc[i][5]+bl[5], acc[i][6]+bl[6], acc[i][7]+bl[7]);
    *(float4*)(C + row*4096 + c0)     = o0;
    *(float4*)(C + row*4096 + c0 + 4) = o1;
  }
}

extern "C" void kernel_launch(void* const* d_in, const int* in_sizes, int n_in,
                              void* d_out, int out_size, void* d_ws, size_t ws_size,
                              hipStream_t stream)
{
  const float* key    = (const float*)d_in[0];
  const float* values = (const float*)d_in[1];
  // d_in[2] = lens (unused by reference path)
  const int*   text   = (const int*)  d_in[3];
  const float* emb    = (const float*)d_in[4];
  const float* Wi1    = (const float*)d_in[5];
  const float* Wh1    = (const float*)d_in[6];
  const float* bi1    = (const float*)d_in[7];
  const float* bh1    = (const float*)d_in[8];
  const float* Wi2    = (const float*)d_in[9];
  const float* Wh2    = (const float*)d_in[10];
  const float* bi2    = (const float*)d_in[11];
  const float* bh2    = (const float*)d_in[12];
  const float* bout   = (const float*)d_in[13];

  // workspace (floats):
  // states[16384*256] | W1T[4*384*256] | W2T[4*384*128] | h1buf[64*256] | h2buf[64*128]
  // | axc[64*4*132] | cnt[64*4 uint]   (~19.4 MB)
  float* states = (float*)d_ws;
  float* W1T    = states + (size_t)BB*LL*256;
  float* W2T    = W1T + (size_t)NB*384*256;
  float* h1buf  = W2T + (size_t)NB*384*128;
  float* h2buf  = h1buf + (size_t)BB*256;
  float* axc    = h2buf + (size_t)BB*128;
  unsigned int* cnt = (unsigned int*)(axc + (size_t)BB*NB*132);

  // scratch inside d_out (268 MB; dead until final GEMM overwrites it):
  // P1[16384*1024] (64 MB) | keyT[64*128*512] (16 MB)
  float* P1   = (float*)d_out;
  float* keyT = P1 + (size_t)16384*1024;

  prep_w   <<<1536, 256, 0, stream>>>(Wi1, Wh1, Wi2, Wh2, W1T, W2T, cnt);
  prep_keyT<<<4096, 256, 0, stream>>>(key, keyT);
  pre_gemm <<<dim3(1024/128, 16384/128), 256, 0, stream>>>(text, emb, Wi1, bi1, bh1, P1);
  rec_kernel<<<BB*NB, 1024, 0, stream>>>(keyT, values, P1, W1T, W2T, bi2, bh2, states,
                                         h1buf, h2buf, axc, cnt);
  dim3 grid(VOC/128, (BB*LL)/128);
  gemm_kernel<<<grid, 256, 0, stream>>>(states, emb, bout, (float*)d_out);
}

// Round 4
// 6052.706 us; speedup vs baseline: 2.9433x; 1.2480x over previous
//
#include <hip/hip_runtime.h>
#include <math.h>

// Problem dims
#define BB   64
#define TT   512
#define LL   256
#define HIDD 256
#define KEYDD 128
#define VALDD 128
#define VOC  4096
#define NB   4        // blocks cooperating per batch element

__device__ __forceinline__ float sigm(float x){ return 1.0f/(1.0f+__expf(-x)); }

// Cache-bypassing system-scope relaxed accesses (sc0 sc1): data goes to/from the
// memory-side coherence point. No cache invalidation, no L2 writeback fences.
// Ordering: writers drain vmcnt(0) at __syncthreads before tid0's arrive-add;
// readers spin on tid0 then cross __syncthreads before issuing data loads.
__device__ __forceinline__ void g_store(float* p, float v){
  __hip_atomic_store(p, v, __ATOMIC_RELAXED, __HIP_MEMORY_SCOPE_SYSTEM);
}
__device__ __forceinline__ float g_load(const float* p){
  return __hip_atomic_load(p, __ATOMIC_RELAXED, __HIP_MEMORY_SCOPE_SYSTEM);
}
__device__ __forceinline__ unsigned ld_cnt(const unsigned int* p){
  return __hip_atomic_load(p, __ATOMIC_RELAXED, __HIP_MEMORY_SCOPE_SYSTEM);
}

// ---------------------------------------------------------------------------
// One-time weight reshapes + counter zeroing.
// W1T [NB][384][256]: rows 0..255 = W_hh1 (h1prev), rows 256..383 = W_ih1 ctx cols.
//   col jj = gate*64 + cell; j = gate*256 + r*64 + cell.
// W2T [NB][384][128]: rows 0..127 = W_hh2 (h2prev), rows 128..383 = W_ih2 (h1).
//   col jj = gate*32 + cell; j = gate*128 + r*32 + cell.
__global__ void prep_w(const float* __restrict__ Wi1, const float* __restrict__ Wh1,
                       const float* __restrict__ Wi2, const float* __restrict__ Wh2,
                       float* __restrict__ W1T, float* __restrict__ W2T,
                       unsigned int* __restrict__ cnt){
  int idx = blockIdx.x*blockDim.x + threadIdx.x;
  if (idx < NB*384*256){
    int r  = idx / (384*256);
    int rm = idx - r*(384*256);
    int k  = rm >> 8, jj = rm & 255;
    int j  = (jj >> 6)*256 + r*64 + (jj & 63);
    W1T[idx] = (k < 256) ? Wh1[j*256 + k] : Wi1[j*384 + 256 + (k-256)];
  }
  if (idx < NB*384*128){
    int r  = idx / (384*128);
    int rm = idx - r*(384*128);
    int k  = rm >> 7, jj = rm & 127;
    int j  = (jj >> 5)*128 + r*32 + (jj & 31);
    W2T[idx] = (k < 128) ? Wh2[j*128 + k] : Wi2[j*256 + (k-128)];
  }
  if (idx < BB*3*64) cnt[idx] = 0;   // padded counters: 3 per group, 256B apart
}

// key [B][T][K] -> keyT [B][K][T], 32x32 LDS tiles (both sides coalesced)
__global__ __launch_bounds__(256) void prep_keyT(const float* __restrict__ key,
                                                 float* __restrict__ keyT){
  __shared__ float tile[32][33];
  int bid = blockIdx.x;
  int b  = bid >> 6;
  int r  = bid & 63;
  int st = r >> 2, kt = r & 3;
  int s0 = st*32, k0 = kt*32;
  int tid = threadIdx.x;
  int kl = tid & 31, sl = tid >> 5;
  #pragma unroll
  for (int i = 0; i < 4; ++i)
    tile[sl + 8*i][kl] = key[((size_t)b*TT + s0 + sl + 8*i)*KEYDD + k0 + kl];
  __syncthreads();
  int sl2 = tid & 31, kl2 = tid >> 5;
  #pragma unroll
  for (int i = 0; i < 4; ++i)
    keyT[((size_t)b*KEYDD + k0 + kl2 + 8*i)*TT + s0 + sl2] = tile[sl2][kl2 + 8*i];
}

// ---------------------------------------------------------------------------
// P1[n][j] = sum_{k<256} emb[text[n]][k] * W_ih1[j][k] + bi1[j] + bh1[j]
__global__ __launch_bounds__(256) void pre_gemm(
    const int*   __restrict__ text, const float* __restrict__ emb,
    const float* __restrict__ Wi1,  const float* __restrict__ bi1,
    const float* __restrict__ bh1,  float* __restrict__ P1)
{
  __shared__ float As[16][132];
  __shared__ float Bs[16][132];
  const int tid = threadIdx.x;
  const int tx = tid & 15, ty = tid >> 4;
  const int bn = blockIdx.x, bm = blockIdx.y;

  float acc[8][8];
  #pragma unroll
  for (int i = 0; i < 8; ++i)
    #pragma unroll
    for (int j = 0; j < 8; ++j) acc[i][j] = 0.f;

  const int r  = tid >> 1;
  const int ko = (tid & 1) * 8;
  const int arow = text[bm*128 + r];
  const float* Ap = emb + (size_t)arow*256 + ko;
  const float* Bp = Wi1 + (size_t)(bn*128 + r)*384 + ko;

  for (int k0 = 0; k0 < 256; k0 += 16){
    float4 a0 = *(const float4*)(Ap + k0);
    float4 a1 = *(const float4*)(Ap + k0 + 4);
    float4 b0 = *(const float4*)(Bp + k0);
    float4 b1 = *(const float4*)(Bp + k0 + 4);
    As[ko+0][r]=a0.x; As[ko+1][r]=a0.y; As[ko+2][r]=a0.z; As[ko+3][r]=a0.w;
    As[ko+4][r]=a1.x; As[ko+5][r]=a1.y; As[ko+6][r]=a1.z; As[ko+7][r]=a1.w;
    Bs[ko+0][r]=b0.x; Bs[ko+1][r]=b0.y; Bs[ko+2][r]=b0.z; Bs[ko+3][r]=b0.w;
    Bs[ko+4][r]=b1.x; Bs[ko+5][r]=b1.y; Bs[ko+6][r]=b1.z; Bs[ko+7][r]=b1.w;
    __syncthreads();
    #pragma unroll
    for (int k = 0; k < 16; ++k){
      float4 x0 = *(const float4*)&As[k][ty*8];
      float4 x1 = *(const float4*)&As[k][ty*8+4];
      float4 y0 = *(const float4*)&Bs[k][tx*8];
      float4 y1 = *(const float4*)&Bs[k][tx*8+4];
      float av[8] = {x0.x,x0.y,x0.z,x0.w,x1.x,x1.y,x1.z,x1.w};
      float bv[8] = {y0.x,y0.y,y0.z,y0.w,y1.x,y1.y,y1.z,y1.w};
      #pragma unroll
      for (int i = 0; i < 8; ++i)
        #pragma unroll
        for (int j = 0; j < 8; ++j) acc[i][j] += av[i]*bv[j];
    }
    __syncthreads();
  }

  const int c0 = bn*128 + tx*8;
  float bl[8];
  #pragma unroll
  for (int j = 0; j < 8; ++j) bl[j] = bi1[c0 + j] + bh1[c0 + j];
  #pragma unroll
  for (int i = 0; i < 8; ++i){
    size_t row = (size_t)(bm*128 + ty*8 + i);
    float4 o0 = make_float4(acc[i][0]+bl[0], acc[i][1]+bl[1], acc[i][2]+bl[2], acc[i][3]+bl[3]);
    float4 o1 = make_float4(acc[i][4]+bl[4], acc[i][5]+bl[5], acc[i][6]+bl[6], acc[i][7]+bl[7]);
    *(float4*)(P1 + row*1024 + c0)     = o0;
    *(float4*)(P1 + row*1024 + c0 + 4) = o1;
  }
}

// ---------------------------------------------------------------------------
// Recurrence: NB=4 blocks per batch element, 1024 threads each (grid = 256).
// Fence-free sync: padded relaxed-system counters; exchange data via sc0sc1
// bypass loads/stores. Sync latency hidden under re-ordered partial GEMVs:
//   ctx-exchange  under LSTM1's h1prev portion (2/3 of W1 stream)
//   h1-exchange   under LSTM2's h2prev portion
//   h2-exchange   under P1 prefetch
__global__ __launch_bounds__(1024) void rec_kernel(
    const float* __restrict__ keyT, const float* __restrict__ values,
    const float* __restrict__ P1,   const float* __restrict__ W1T,
    const float* __restrict__ W2T,  const float* __restrict__ bi2,
    const float* __restrict__ bh2,  float* __restrict__ states,
    float* __restrict__ h1buf, float* __restrict__ h2buf,
    float* __restrict__ axc,  unsigned int* __restrict__ cnt)
{
  const int bid = blockIdx.x;
  const int b = bid >> 2, r = bid & 3;
  const int tid = threadIdx.x;

  __shared__ __align__(16) float ST[512];     // [ctx 0:128 | h1 128:384 | h2 384:512]
  __shared__ __align__(16) float part[4096];
  __shared__ float g1s[256];
  __shared__ float att[128];
  __shared__ float b2loc[128];
  __shared__ float red[4];

  if (tid < 512) ST[tid] = 0.f;
  if (tid < 128){
    int j = (tid >> 5)*128 + r*32 + (tid & 31);
    b2loc[tid] = bi2[j] + bh2[j];
  }
  float c1 = 0.f, c2 = 0.f;
  __syncthreads();

  const float4* W1r4  = reinterpret_cast<const float4*>(W1T) + (size_t)r*384*64;
  const float4* W2r4  = reinterpret_cast<const float4*>(W2T) + (size_t)r*384*32;
  const float4* keyB4 = reinterpret_cast<const float4*>(keyT + (size_t)b*KEYDD*TT);
  const float4* valB4 = reinterpret_cast<const float4*>(values + (size_t)b*TT*VALDD);
  const float*  P1row = P1 + (size_t)b*LL*1024;
  unsigned int* cA = cnt + (b*3 + 0)*64;
  unsigned int* cB = cnt + (b*3 + 1)*64;
  unsigned int* cC = cnt + (b*3 + 2)*64;
  float* axb = axc + (size_t)b*NB*132;
  float* h1g = h1buf + b*256;
  float* h2g = h2buf + b*128;

  const int ogA = tid & 63, kcA = tid >> 6;   // LSTM1: 64 out-groups(x4) x 16 k-chunks
  const int ogB = tid & 31, kcB = tid >> 5;   // LSTM2/attn: 32 groups(x4) x 32 chunks

  float p1v = (tid < 256) ? P1row[(tid >> 6)*256 + r*64 + (tid & 63)] : 0.f;

  for (int t = 0; t < LL; ++t, P1row += 1024){   // <-- FIX: advance P1row per step
    // ---- A1: LSTM1 partials, h1prev portion (W1 rows 0..255) — runs under ctx flight
    float4 accA = make_float4(0.f,0.f,0.f,0.f);
    {
      const float4* wp = W1r4 + (size_t)(kcA*16)*64 + ogA;
      #pragma unroll 8
      for (int i = 0; i < 16; ++i){
        float4 w = wp[(size_t)i*64];
        float  x = ST[128 + kcA*16 + i];
        accA.x += x*w.x; accA.y += x*w.y; accA.z += x*w.z; accA.w += x*w.w;
      }
    }
    // ---- wait ctx exchange of step t-1, flash combine
    if (t > 0){
      if (tid == 0){
        while (ld_cnt(cC) < (unsigned)(t*NB)) __builtin_amdgcn_s_sleep(1);
      }
      __syncthreads();
      if (tid < 128){
        float m0 = g_load(axb+128),     m1 = g_load(axb+132+128);
        float m2 = g_load(axb+264+128), m3 = g_load(axb+396+128);
        float s0 = g_load(axb+129),     s1 = g_load(axb+132+129);
        float s2 = g_load(axb+264+129), s3 = g_load(axb+396+129);
        float x0 = g_load(axb+tid),     x1 = g_load(axb+132+tid);
        float x2 = g_load(axb+264+tid), x3 = g_load(axb+396+tid);
        float M  = fmaxf(fmaxf(m0,m1), fmaxf(m2,m3));
        float w0 = __expf(m0-M), w1 = __expf(m1-M), w2 = __expf(m2-M), w3 = __expf(m3-M);
        float inv = 1.0f/(w0*s0 + w1*s1 + w2*s2 + w3*s3);
        float cx  = (w0*x0 + w1*x1 + w2*x2 + w3*x3)*inv;
        ST[tid] = cx;
        if ((tid >> 5) == r)
          states[((size_t)b*LL + (t-1))*256 + 128 + tid] = cx;
      }
    }
    __syncthreads();

    // ---- A2: ctx portion (W1 rows 256..383)
    {
      const float4* wp = W1r4 + (size_t)(256 + kcA*8)*64 + ogA;
      #pragma unroll
      for (int i = 0; i < 8; ++i){
        float4 w = wp[(size_t)i*64];
        float  x = ST[kcA*8 + i];
        accA.x += x*w.x; accA.y += x*w.y; accA.z += x*w.z; accA.w += x*w.w;
      }
    }
    *reinterpret_cast<float4*>(&part[kcA*256 + ogA*4]) = accA;
    __syncthreads();
    if (tid < 256){
      float s = p1v;
      #pragma unroll
      for (int kc = 0; kc < 16; ++kc) s += part[kc*256 + tid];
      g1s[tid] = s;
    }
    __syncthreads();
    if (tid < 64){
      float gi = sigm(g1s[tid]),      gf = sigm(g1s[64+tid]);
      float gg = tanhf(g1s[128+tid]), go = sigm(g1s[192+tid]);
      float c = gf*c1 + gi*gg; c1 = c;
      g_store(h1g + r*64 + tid, go*tanhf(c));
    }
    // arrive h1
    __syncthreads();
    if (tid == 0) __hip_atomic_fetch_add(cA, 1u, __ATOMIC_RELAXED, __HIP_MEMORY_SCOPE_SYSTEM);

    // ---- B1: LSTM2 partials, h2prev portion (W2 rows 0..127) — runs under h1 flight
    float4 accB = make_float4(0.f,0.f,0.f,0.f);
    {
      const float4* wp = W2r4 + (size_t)(kcB*4)*32 + ogB;
      #pragma unroll
      for (int i = 0; i < 4; ++i){
        float4 w = wp[(size_t)i*32];
        float  x = ST[384 + kcB*4 + i];
        accB.x += x*w.x; accB.y += x*w.y; accB.z += x*w.z; accB.w += x*w.w;
      }
    }
    // wait h1, load full h1
    if (tid == 0){
      while (ld_cnt(cA) < (unsigned)((t+1)*NB)) __builtin_amdgcn_s_sleep(1);
    }
    __syncthreads();
    if (tid < 256) ST[128+tid] = g_load(h1g + tid);
    __syncthreads();

    // ---- B2: h1 portion (W2 rows 128..383)
    {
      const float4* wp = W2r4 + (size_t)(128 + kcB*8)*32 + ogB;
      #pragma unroll
      for (int i = 0; i < 8; ++i){
        float4 w = wp[(size_t)i*32];
        float  x = ST[128 + kcB*8 + i];
        accB.x += x*w.x; accB.y += x*w.y; accB.z += x*w.z; accB.w += x*w.w;
      }
    }
    *reinterpret_cast<float4*>(&part[kcB*128 + ogB*4]) = accB;
    __syncthreads();
    if (tid < 128){
      float s = b2loc[tid];
      #pragma unroll
      for (int kc = 0; kc < 32; ++kc) s += part[kc*128 + tid];
      g1s[tid] = s;
    }
    __syncthreads();
    if (tid < 32){
      float gi = sigm(g1s[tid]),     gf = sigm(g1s[32+tid]);
      float gg = tanhf(g1s[64+tid]), go = sigm(g1s[96+tid]);
      float c = gf*c2 + gi*gg; c2 = c;
      float h2 = go*tanhf(c);
      g_store(h2g + r*32 + tid, h2);
      states[((size_t)b*LL + t)*256 + r*32 + tid] = h2;
    }
    // arrive h2
    __syncthreads();
    if (tid == 0) __hip_atomic_fetch_add(cB, 1u, __ATOMIC_RELAXED, __HIP_MEMORY_SCOPE_SYSTEM);

    // prefetch next step's P1 (hides h2 flight)
    if (t+1 < LL && tid < 256)
      p1v = P1row[1024 + (tid >> 6)*256 + r*64 + (tid & 63)];

    // wait h2, load full h2
    if (tid == 0){
      while (ld_cnt(cB) < (unsigned)((t+1)*NB)) __builtin_amdgcn_s_sleep(1);
    }
    __syncthreads();
    if (tid < 128) ST[384+tid] = g_load(h2g + tid);
    __syncthreads();

    // ---- C: attention energies for s-slice [128r, 128r+128)
    {
      const float4* kp = keyB4 + (size_t)(kcB*4)*128 + r*32 + ogB;
      float4 acc = make_float4(0.f,0.f,0.f,0.f);
      #pragma unroll
      for (int i = 0; i < 4; ++i){
        float4 kv = kp[(size_t)i*128];
        float  h  = ST[384 + kcB*4 + i];
        acc.x += h*kv.x; acc.y += h*kv.y; acc.z += h*kv.z; acc.w += h*kv.w;
      }
      *reinterpret_cast<float4*>(&part[kcB*128 + ogB*4]) = acc;
    }
    __syncthreads();
    float e = 0.f;
    if (tid < 128){
      #pragma unroll
      for (int kc = 0; kc < 32; ++kc) e += part[kc*128 + tid];
    }
    float m = (tid < 128) ? e : -3.4e38f;
    #pragma unroll
    for (int off = 32; off > 0; off >>= 1) m = fmaxf(m, __shfl_xor(m, off));
    if (tid == 0)  red[0] = m;
    if (tid == 64) red[1] = m;
    __syncthreads();
    float M = fmaxf(red[0], red[1]);
    float p = (tid < 128) ? __expf(e - M) : 0.f;
    if (tid < 128) att[tid] = p;
    float ss = p;
    #pragma unroll
    for (int off = 32; off > 0; off >>= 1) ss += __shfl_xor(ss, off);
    if (tid == 0)  red[2] = ss;
    if (tid == 64) red[3] = ss;
    __syncthreads();
    float S = red[2] + red[3];

    // ---- partial context over own s-slice
    {
      const float4* vp = valB4 + (size_t)(r*128 + kcB*4)*32 + ogB;
      float4 acc = make_float4(0.f,0.f,0.f,0.f);
      #pragma unroll
      for (int i = 0; i < 4; ++i){
        float4 vv = vp[(size_t)i*32];
        float  a  = att[kcB*4 + i];
        acc.x += a*vv.x; acc.y += a*vv.y; acc.z += a*vv.z; acc.w += a*vv.w;
      }
      *reinterpret_cast<float4*>(&part[kcB*128 + ogB*4]) = acc;
    }
    __syncthreads();
    if (tid < 128){
      float cx = 0.f;
      #pragma unroll
      for (int kc = 0; kc < 32; ++kc) cx += part[kc*128 + tid];
      g_store(axb + r*132 + tid, cx);
    }
    if (tid == 0){
      g_store(axb + r*132 + 128, M);
      g_store(axb + r*132 + 129, S);
    }
    // arrive ctx
    __syncthreads();
    if (tid == 0) __hip_atomic_fetch_add(cC, 1u, __ATOMIC_RELAXED, __HIP_MEMORY_SCOPE_SYSTEM);
  }

  // ---- epilogue: combine ctx for t = LL-1 (states only)
  if (tid == 0){
    while (ld_cnt(cC) < (unsigned)(LL*NB)) __builtin_amdgcn_s_sleep(1);
  }
  __syncthreads();
  if (tid < 128){
    float m0 = g_load(axb+128),     m1 = g_load(axb+132+128);
    float m2 = g_load(axb+264+128), m3 = g_load(axb+396+128);
    float s0 = g_load(axb+129),     s1 = g_load(axb+132+129);
    float s2 = g_load(axb+264+129), s3 = g_load(axb+396+129);
    float x0 = g_load(axb+tid),     x1 = g_load(axb+132+tid);
    float x2 = g_load(axb+264+tid), x3 = g_load(axb+396+tid);
    float M  = fmaxf(fmaxf(m0,m1), fmaxf(m2,m3));
    float w0 = __expf(m0-M), w1 = __expf(m1-M), w2 = __expf(m2-M), w3 = __expf(m3-M);
    float inv = 1.0f/(w0*s0 + w1*s1 + w2*s2 + w3*s3);
    float cx  = (w0*x0 + w1*x1 + w2*x2 + w3*x3)*inv;
    states[((size_t)b*LL + (LL-1))*256 + 128 + tid] = cx;
  }
}

// ---------------------------------------------------------------------------
// Final logits GEMM: C[n][v] = states[n][:] . emb[v][:] + b_out[v]
__global__ __launch_bounds__(256) void gemm_kernel(
    const float* __restrict__ A, const float* __restrict__ Bm,
    const float* __restrict__ bias, float* __restrict__ C)
{
  __shared__ float As[16][132];
  __shared__ float Bs[16][132];
  const int tid = threadIdx.x;
  const int tx = tid & 15, ty = tid >> 4;
  const int bn = blockIdx.x, bm = blockIdx.y;

  float acc[8][8];
  #pragma unroll
  for (int i = 0; i < 8; ++i)
    #pragma unroll
    for (int j = 0; j < 8; ++j) acc[i][j] = 0.f;

  const int r  = tid >> 1;
  const int ko = (tid & 1) * 8;
  const float* Ap = A  + ((size_t)(bm*128 + r))*256 + ko;
  const float* Bp = Bm + ((size_t)(bn*128 + r))*256 + ko;

  for (int k0 = 0; k0 < 256; k0 += 16){
    float4 a0 = *(const float4*)(Ap + k0);
    float4 a1 = *(const float4*)(Ap + k0 + 4);
    float4 b0 = *(const float4*)(Bp + k0);
    float4 b1 = *(const float4*)(Bp + k0 + 4);
    As[ko+0][r]=a0.x; As[ko+1][r]=a0.y; As[ko+2][r]=a0.z; As[ko+3][r]=a0.w;
    As[ko+4][r]=a1.x; As[ko+5][r]=a1.y; As[ko+6][r]=a1.z; As[ko+7][r]=a1.w;
    Bs[ko+0][r]=b0.x; Bs[ko+1][r]=b0.y; Bs[ko+2][r]=b0.z; Bs[ko+3][r]=b0.w;
    Bs[ko+4][r]=b1.x; Bs[ko+5][r]=b1.y; Bs[ko+6][r]=b1.z; Bs[ko+7][r]=b1.w;
    __syncthreads();
    #pragma unroll
    for (int k = 0; k < 16; ++k){
      float4 x0 = *(const float4*)&As[k][ty*8];
      float4 x1 = *(const float4*)&As[k][ty*8+4];
      float4 y0 = *(const float4*)&Bs[k][tx*8];
      float4 y1 = *(const float4*)&Bs[k][tx*8+4];
      float av[8] = {x0.x,x0.y,x0.z,x0.w,x1.x,x1.y,x1.z,x1.w};
      float bv[8] = {y0.x,y0.y,y0.z,y0.w,y1.x,y1.y,y1.z,y1.w};
      #pragma unroll
      for (int i = 0; i < 8; ++i)
        #pragma unroll
        for (int j = 0; j < 8; ++j) acc[i][j] += av[i]*bv[j];
    }
    __syncthreads();
  }

  const int c0 = bn*128 + tx*8;
  float bl[8];
  #pragma unroll
  for (int j = 0; j < 8; ++j) bl[j] = bias[c0 + j];
  #pragma unroll
  for (int i = 0; i < 8; ++i){
    size_t row = (size_t)(bm*128 + ty*8 + i);
    float4 o0 = make_float4(acc[i][0]+bl[0], acc[i][1]+bl[1], acc[i][2]+bl[2], acc[i][3]+bl[3]);
    float4 o1 = make_float4(acc[i][4]+bl[4], acc[i][5]+bl[5], acc[i][6]+bl[6], acc[i][7]+bl[7]);
    *(float4*)(C + row*4096 + c0)     = o0;
    *(float4*)(C + row*4096 + c0 + 4) = o1;
  }
}

extern "C" void kernel_launch(void* const* d_in, const int* in_sizes, int n_in,
                              void* d_out, int out_size, void* d_ws, size_t ws_size,
                              hipStream_t stream)
{
  const float* key    = (const float*)d_in[0];
  const float* values = (const float*)d_in[1];
  // d_in[2] = lens (unused by reference path)
  const int*   text   = (const int*)  d_in[3];
  const float* emb    = (const float*)d_in[4];
  const float* Wi1    = (const float*)d_in[5];
  const float* Wh1    = (const float*)d_in[6];
  const float* bi1    = (const float*)d_in[7];
  const float* bh1    = (const float*)d_in[8];
  const float* Wi2    = (const float*)d_in[9];
  const float* Wh2    = (const float*)d_in[10];
  const float* bi2    = (const float*)d_in[11];
  const float* bh2    = (const float*)d_in[12];
  const float* bout   = (const float*)d_in[13];

  // workspace (floats): states[16384*256] | W1T[4*384*256] | W2T[4*384*128] (~19.1 MB)
  float* states = (float*)d_ws;
  float* W1T    = states + (size_t)BB*LL*256;
  float* W2T    = W1T + (size_t)NB*384*256;

  // scratch inside d_out (268 MB; dead until final GEMM overwrites it):
  // P1[16384*1024] | keyT[64*128*512] | h1buf[64*256] | h2buf[64*128]
  // | axc[64*4*132] | cnt[64*3*64 uint]
  float* P1    = (float*)d_out;
  float* keyT  = P1 + (size_t)16384*1024;
  float* h1buf = keyT + (size_t)BB*KEYDD*TT;
  float* h2buf = h1buf + (size_t)BB*256;
  float* axc   = h2buf + (size_t)BB*128;
  unsigned int* cnt = (unsigned int*)(axc + (size_t)BB*NB*132);

  prep_w   <<<1536, 256, 0, stream>>>(Wi1, Wh1, Wi2, Wh2, W1T, W2T, cnt);
  prep_keyT<<<4096, 256, 0, stream>>>(key, keyT);
  pre_gemm <<<dim3(1024/128, 16384/128), 256, 0, stream>>>(text, emb, Wi1, bi1, bh1, P1);
  rec_kernel<<<BB*NB, 1024, 0, stream>>>(keyT, values, P1, W1T, W2T, bi2, bh2, states,
                                         h1buf, h2buf, axc, cnt);
  dim3 grid(VOC/128, (BB*LL)/128);
  gemm_kernel<<<grid, 256, 0, stream>>>(states, emb, bout, (float*)d_out);
}